// Round 14
// baseline (878.152 us; speedup 1.0000x reference)
//
#include <hip/hip_runtime.h>
#include <hip/hip_fp16.h>
#include <cmath>

static constexpr int NN = 100000;   // nodes
static constexpr int NE = 1600000;  // edges
static const size_t NW = (size_t)NN * 32;
static constexpr int SUB = 256;         // nodes per sub-slice (LDS accumulator)
static constexpr int NSUB = 391;        // ceil(NN/SUB)
static constexpr int CH = 8192;         // edges per bucket-build chunk
static constexpr int NCH = (NE + CH - 1) / CH;  // 196
static constexpr int BCAP = 5200;       // per-sub-slice bucket cap (mean 4092)
static constexpr int MCAP = 4096;       // masked-node list capacity

// bucket entry: x = src(17b) | fp16(ew)<<17 ; y = global dst
__device__ __forceinline__ float ent_w(unsigned e)
{
    return __half2float(__ushort_as_half((unsigned short)(e >> 17)));
}
__device__ __forceinline__ int ent_s(unsigned e)
{
    int s = (int)(e & 0x1FFFF);
    return s < NN ? s : NN - 1;   // hardened: OOB -> wrong value, not fault
}

__device__ __forceinline__ float4 pack8(const float* v)
{
    union { __half2 h2[4]; float4 f4; } u;
    u.h2[0] = __floats2half2_rn(v[0], v[1]);
    u.h2[1] = __floats2half2_rn(v[2], v[3]);
    u.h2[2] = __floats2half2_rn(v[4], v[5]);
    u.h2[3] = __floats2half2_rn(v[6], v[7]);
    return u.f4;
}

// ---------------------------------------------------------------------------
// countC: per-(chunk, sub-slice) histogram via LDS + mask collection.
// ---------------------------------------------------------------------------
__global__ void __launch_bounds__(512) countC_k(
    const int* __restrict__ src, const int* __restrict__ dst,
    const int* __restrict__ curp, int* __restrict__ maskb,
    int* __restrict__ mcount, int* __restrict__ mlist,
    int* __restrict__ blkcnt)
{
    __shared__ int lhist[NSUB];
    int t = threadIdx.x;
    for (int i = t; i < NSUB; i += 512) lhist[i] = 0;
    __syncthreads();
    int c0 = blockIdx.x * CH;
    int cur = curp[0];
#pragma unroll
    for (int it = 0; it < CH / 512; ++it) {
        int e = c0 + it * 512 + t;
        if (e < NE) {
            int d = dst[e];
            if ((unsigned)d < (unsigned)NN) {
                atomicAdd(&lhist[d >> 8], 1);
                if (src[e] == cur) {
                    if (atomicExch(maskb + d, 1) == 0) {
                        int idx = atomicAdd(mcount, 1);
                        if (idx < MCAP) mlist[idx] = d;
                    }
                }
            }
        }
    }
    __syncthreads();
    for (int b = t; b < NSUB; b += 512)
        blkcnt[b * NCH + blockIdx.x] = lhist[b];
}

// scan chunks within each sub-slice bucket: blkbase (excl), btot.
__global__ void __launch_bounds__(256) scan_blk_k(
    const int* __restrict__ blkcnt, int* __restrict__ blkbase,
    int* __restrict__ btot)
{
    __shared__ int tmp[256];
    int b = blockIdx.x, t = threadIdx.x;
    int v = (t < NCH) ? blkcnt[b * NCH + t] : 0;
    tmp[t] = v;
    __syncthreads();
    for (int s = 1; s < 256; s <<= 1) {
        int x = tmp[t];
        int a = (t >= s) ? tmp[t - s] : 0;
        __syncthreads();
        tmp[t] = x + a;
        __syncthreads();
    }
    if (t < NCH) blkbase[b * NCH + t] = tmp[t] - v;
    if (t == 255) btot[b] = tmp[255];
}

// ---------------------------------------------------------------------------
// writeC: stage chunk in registers, LDS-sort by sub-slice, dump grouped
// (consecutive threads -> consecutive bucket addresses, ~330B segments).
// Deterministic bases (scanned); only LDS atomics (391 counters, low contention).
// ---------------------------------------------------------------------------
__global__ void __launch_bounds__(512) writeC_k(
    const int* __restrict__ src, const int* __restrict__ dst,
    const float* __restrict__ ew, const int* __restrict__ blkbase,
    uint2* __restrict__ buckets)
{
    __shared__ uint2 sBuf[CH];          // 64 KB
    __shared__ int lhist[NSUB];
    __shared__ int lpos[NSUB];
    __shared__ int lstart[NSUB];
    __shared__ int lbase[NSUB];
    __shared__ int tscan[512];
    int t = threadIdx.x;
    for (int i = t; i < NSUB; i += 512) { lhist[i] = 0; lpos[i] = 0; }
    __syncthreads();
    int c0 = blockIdx.x * CH;
    uint2 rent[CH / 512];
    int rb[CH / 512];
#pragma unroll
    for (int it = 0; it < CH / 512; ++it) {
        int e = c0 + it * 512 + t;
        rb[it] = -1;
        if (e < NE) {
            int d = dst[e];
            if ((unsigned)d < (unsigned)NN) {
                rb[it] = d >> 8;
                unsigned bits = __half_as_ushort(__float2half(ew[e]));
                rent[it].x = ((unsigned)src[e] & 0x1FFFF) | (bits << 17);
                rent[it].y = (unsigned)d;
                atomicAdd(&lhist[rb[it]], 1);
            }
        }
    }
    __syncthreads();
    // 512-wide exclusive scan of lhist -> lstart
    int v = (t < NSUB) ? lhist[t] : 0;
    tscan[t] = v;
    __syncthreads();
    for (int s = 1; s < 512; s <<= 1) {
        int x = tscan[t];
        int a = (t >= s) ? tscan[t - s] : 0;
        __syncthreads();
        tscan[t] = x + a;
        __syncthreads();
    }
    if (t < NSUB) {
        lstart[t] = tscan[t] - v;
        lbase[t] = blkbase[t * NCH + blockIdx.x];
    }
    __syncthreads();
#pragma unroll
    for (int it = 0; it < CH / 512; ++it) {
        if (rb[it] >= 0) {
            int p = atomicAdd(&lpos[rb[it]], 1);
            sBuf[lstart[rb[it]] + p] = rent[it];
        }
    }
    __syncthreads();
    int total = lstart[NSUB - 1] + lhist[NSUB - 1];
    for (int j = t; j < total; j += 512) {
        uint2 e = sBuf[j];
        int b = (int)(e.y >> 8);
        if (b >= NSUB) b = NSUB - 1;
        unsigned pos = (unsigned)(lbase[b] + (j - lstart[b]));
        if (pos < (unsigned)BCAP) buckets[(size_t)b * BCAP + pos] = e;
    }
}

// ---------------------------------------------------------------------------
// mm1: proj1 = fp16(x@Win_rel), root1 = fp16(x@Win_root + bin).
// ---------------------------------------------------------------------------
__global__ void __launch_bounds__(256) mm1_k(
    const float* __restrict__ x, const float* __restrict__ Wrel,
    const float* __restrict__ Wroot, const float* __restrict__ bin,
    __half* __restrict__ proj1, __half* __restrict__ root1)
{
    __shared__ float sX[128 * 65];
    __shared__ float sW[64 * 68];
    int t = threadIdx.x;
    for (int i = t; i < 64 * 32; i += 256) {
        int k = i >> 5, j = i & 31;
        sW[k * 68 + j] = Wrel[i];
        sW[k * 68 + 32 + j] = Wroot[i];
    }
    int base = blockIdx.x * 128;
    for (int i = t; i < 2048; i += 256) {
        int node = i >> 4;
        int k = (i & 15) * 4;
        int n = base + node;
        if (n >= NN) n = NN - 1;
        float4 v = *(const float4*)(x + (size_t)n * 64 + k);
        float* p = sX + node * 65 + k;
        p[0] = v.x; p[1] = v.y; p[2] = v.z; p[3] = v.w;
    }
    __syncthreads();
    int cg = t & 7;
    int ng = t >> 3;
    int c0 = 8 * cg;
    float acc[4][8] = {};
    for (int k = 0; k < 64; ++k) {
        float xv0 = sX[(4 * ng + 0) * 65 + k];
        float xv1 = sX[(4 * ng + 1) * 65 + k];
        float xv2 = sX[(4 * ng + 2) * 65 + k];
        float xv3 = sX[(4 * ng + 3) * 65 + k];
        float4 w0 = *(const float4*)(sW + k * 68 + c0);
        float4 w1 = *(const float4*)(sW + k * 68 + c0 + 4);
        const float* wp = (const float*)&w0;
#pragma unroll
        for (int j = 0; j < 4; ++j) {
            float w = wp[j];
            acc[0][j] = fmaf(xv0, w, acc[0][j]);
            acc[1][j] = fmaf(xv1, w, acc[1][j]);
            acc[2][j] = fmaf(xv2, w, acc[2][j]);
            acc[3][j] = fmaf(xv3, w, acc[3][j]);
        }
        const float* wq = (const float*)&w1;
#pragma unroll
        for (int j = 0; j < 4; ++j) {
            float w = wq[j];
            acc[0][4 + j] = fmaf(xv0, w, acc[0][4 + j]);
            acc[1][4 + j] = fmaf(xv1, w, acc[1][4 + j]);
            acc[2][4 + j] = fmaf(xv2, w, acc[2][4 + j]);
            acc[3][4 + j] = fmaf(xv3, w, acc[3][4 + j]);
        }
    }
#pragma unroll
    for (int r = 0; r < 4; ++r) {
        int n = base + 4 * ng + r;
        if (n >= NN) break;
        if (cg < 4) {
            *(float4*)(proj1 + (size_t)n * 32 + c0) = pack8(acc[r]);
        } else {
            int c = c0 - 32;
            float v[8];
#pragma unroll
            for (int j = 0; j < 8; ++j) v[j] = acc[r][j] + bin[c + j];
            *(float4*)(root1 + (size_t)n * 32 + c) = pack8(v);
        }
    }
}

// ---------------------------------------------------------------------------
// mm2: proj2 = fp16(h1@Wh_rel), root2 = fp16(h1@Wh_root + bh). K=32.
// ---------------------------------------------------------------------------
__global__ void __launch_bounds__(256) mm2_k(
    const __half* __restrict__ h1, const float* __restrict__ Wrel,
    const float* __restrict__ Wroot, const float* __restrict__ bh,
    __half* __restrict__ proj2, __half* __restrict__ root2)
{
    __shared__ float sX[128 * 33];
    __shared__ float sW[32 * 68];
    int t = threadIdx.x;
    for (int i = t; i < 32 * 32; i += 256) {
        int k = i >> 5, j = i & 31;
        sW[k * 68 + j] = Wrel[i];
        sW[k * 68 + 32 + j] = Wroot[i];
    }
    int base = blockIdx.x * 128;
    for (int i = t; i < 512; i += 256) {
        int node = i >> 2;
        int hs = (i & 3) * 8;
        int n = base + node;
        if (n >= NN) n = NN - 1;
        float4 v = *(const float4*)(h1 + (size_t)n * 32 + hs);
        const __half2* hp = (const __half2*)&v;
        float* p = sX + node * 33 + hs;
#pragma unroll
        for (int u = 0; u < 4; ++u) {
            float2 f2 = __half22float2(hp[u]);
            p[2 * u] = f2.x;
            p[2 * u + 1] = f2.y;
        }
    }
    __syncthreads();
    int cg = t & 7;
    int ng = t >> 3;
    int c0 = 8 * cg;
    float acc[4][8] = {};
    for (int k = 0; k < 32; ++k) {
        float xv0 = sX[(4 * ng + 0) * 33 + k];
        float xv1 = sX[(4 * ng + 1) * 33 + k];
        float xv2 = sX[(4 * ng + 2) * 33 + k];
        float xv3 = sX[(4 * ng + 3) * 33 + k];
        float4 w0 = *(const float4*)(sW + k * 68 + c0);
        float4 w1 = *(const float4*)(sW + k * 68 + c0 + 4);
        const float* wp = (const float*)&w0;
#pragma unroll
        for (int j = 0; j < 4; ++j) {
            float w = wp[j];
            acc[0][j] = fmaf(xv0, w, acc[0][j]);
            acc[1][j] = fmaf(xv1, w, acc[1][j]);
            acc[2][j] = fmaf(xv2, w, acc[2][j]);
            acc[3][j] = fmaf(xv3, w, acc[3][j]);
        }
        const float* wq = (const float*)&w1;
#pragma unroll
        for (int j = 0; j < 4; ++j) {
            float w = wq[j];
            acc[0][4 + j] = fmaf(xv0, w, acc[0][4 + j]);
            acc[1][4 + j] = fmaf(xv1, w, acc[1][4 + j]);
            acc[2][4 + j] = fmaf(xv2, w, acc[2][4 + j]);
            acc[3][4 + j] = fmaf(xv3, w, acc[3][4 + j]);
        }
    }
#pragma unroll
    for (int r = 0; r < 4; ++r) {
        int n = base + 4 * ng + r;
        if (n >= NN) break;
        if (cg < 4) {
            *(float4*)(proj2 + (size_t)n * 32 + c0) = pack8(acc[r]);
        } else {
            int c = c0 - 32;
            float v[8];
#pragma unroll
            for (int j = 0; j < 8; ++j) v[j] = acc[r][j] + bh[c + j];
            *(float4*)(root2 + (size_t)n * 32 + c) = pack8(v);
        }
    }
}

// ---------------------------------------------------------------------------
// agg1_lds: scatter-add w*proj1[src] into 33-padded LDS accumulator for this
// 256-node sub-slice (bank = (ld+f)%32 -> spread); epilogue adds root+ReLU,
// writes h1. 2 threads/edge (16 feats each). No CSR, no global scatter.
// ---------------------------------------------------------------------------
__global__ void __launch_bounds__(512) agg1_lds_k(
    const __half* __restrict__ proj1, const __half* __restrict__ root1,
    const uint2* __restrict__ buckets, const int* __restrict__ btot,
    __half* __restrict__ h1)
{
    __shared__ float acc[SUB * 33];   // 33.8 KB
    int t = threadIdx.x, g = blockIdx.x;
    for (int i = t; i < SUB * 33; i += 512) acc[i] = 0.f;
    __syncthreads();
    int cnt = btot[g];
    if (cnt < 0) cnt = 0;
    if (cnt > BCAP) cnt = BCAP;
    const uint2* bk = buckets + (size_t)g * BCAP;
    int h = t & 1, hb = h * 16;
    for (int i = t >> 1; i < cnt; i += 256) {
        uint2 e = bk[i];
        int s = ent_s(e.x);
        float w = ent_w(e.x);
        int ld = e.y & (SUB - 1);
        const float4* rp = (const float4*)(proj1 + (size_t)s * 32 + hb);
        float4 r0 = rp[0], r1 = rp[1];
        union { float4 f4; __half2 h2[4]; } u0, u1;
        u0.f4 = r0; u1.f4 = r1;
        float* a = acc + ld * 33 + hb;
#pragma unroll
        for (int k = 0; k < 4; ++k) {
            float2 xx = __half22float2(u0.h2[k]);
            atomicAdd(a + 2 * k, w * xx.x);
            atomicAdd(a + 2 * k + 1, w * xx.y);
        }
#pragma unroll
        for (int k = 0; k < 4; ++k) {
            float2 xx = __half22float2(u1.h2[k]);
            atomicAdd(a + 8 + 2 * k, w * xx.x);
            atomicAdd(a + 8 + 2 * k + 1, w * xx.y);
        }
    }
    __syncthreads();
    int ld = t >> 1;
    int n = g * SUB + ld;
    if (n < NN) {
        const float4* rr = (const float4*)(root1 + (size_t)n * 32 + hb);
        float4 q0 = rr[0], q1 = rr[1];
        union { float4 f4; __half2 h2[4]; } v0, v1;
        v0.f4 = q0; v1.f4 = q1;
        float hv[16];
        const float* a = acc + ld * 33 + hb;
#pragma unroll
        for (int k = 0; k < 4; ++k) {
            float2 xx = __half22float2(v0.h2[k]);
            hv[2 * k] = fmaxf(a[2 * k] + xx.x, 0.f);
            hv[2 * k + 1] = fmaxf(a[2 * k + 1] + xx.y, 0.f);
        }
#pragma unroll
        for (int k = 0; k < 4; ++k) {
            float2 xx = __half22float2(v1.h2[k]);
            hv[8 + 2 * k] = fmaxf(a[8 + 2 * k] + xx.x, 0.f);
            hv[8 + 2 * k + 1] = fmaxf(a[8 + 2 * k + 1] + xx.y, 0.f);
        }
        float4* op = (float4*)(h1 + (size_t)n * 32 + hb);
        op[0] = pack8(hv);
        op[1] = pack8(hv + 8);
    }
}

// ---------------------------------------------------------------------------
// agg2_lds: same scatter on proj2; epilogue = root+ReLU + 4 OUT=1 head dots
// -> pv (rel parts), pbase/vbase (root parts + bias).
// ---------------------------------------------------------------------------
__global__ void __launch_bounds__(512) agg2_lds_k(
    const __half* __restrict__ proj2, const __half* __restrict__ root2,
    const float* __restrict__ Wp_rel, const float* __restrict__ Wp_root,
    const float* __restrict__ bp, const float* __restrict__ Wv_rel,
    const float* __restrict__ Wv_root, const float* __restrict__ bv,
    const uint2* __restrict__ buckets, const int* __restrict__ btot,
    float2* __restrict__ pv, float* __restrict__ pbase,
    float* __restrict__ vbase)
{
    __shared__ float acc[SUB * 33];
    __shared__ float sHead[128];
    int t = threadIdx.x, g = blockIdx.x;
    for (int i = t; i < SUB * 33; i += 512) acc[i] = 0.f;
    if (t < 128) {
        sHead[t] = (t < 32) ? Wp_rel[t]
                 : (t < 64) ? Wp_root[t - 32]
                 : (t < 96) ? Wv_rel[t - 64] : Wv_root[t - 96];
    }
    __syncthreads();
    int cnt = btot[g];
    if (cnt < 0) cnt = 0;
    if (cnt > BCAP) cnt = BCAP;
    const uint2* bk = buckets + (size_t)g * BCAP;
    int h = t & 1, hb = h * 16;
    for (int i = t >> 1; i < cnt; i += 256) {
        uint2 e = bk[i];
        int s = ent_s(e.x);
        float w = ent_w(e.x);
        int ld = e.y & (SUB - 1);
        const float4* rp = (const float4*)(proj2 + (size_t)s * 32 + hb);
        float4 r0 = rp[0], r1 = rp[1];
        union { float4 f4; __half2 h2[4]; } u0, u1;
        u0.f4 = r0; u1.f4 = r1;
        float* a = acc + ld * 33 + hb;
#pragma unroll
        for (int k = 0; k < 4; ++k) {
            float2 xx = __half22float2(u0.h2[k]);
            atomicAdd(a + 2 * k, w * xx.x);
            atomicAdd(a + 2 * k + 1, w * xx.y);
        }
#pragma unroll
        for (int k = 0; k < 4; ++k) {
            float2 xx = __half22float2(u1.h2[k]);
            atomicAdd(a + 8 + 2 * k, w * xx.x);
            atomicAdd(a + 8 + 2 * k + 1, w * xx.y);
        }
    }
    __syncthreads();
    int ld = t >> 1;
    int n = g * SUB + ld;
    float pr = 0.f, po = 0.f, vr = 0.f, vo = 0.f;
    if (n < NN) {
        const float4* rr = (const float4*)(root2 + (size_t)n * 32 + hb);
        float4 q0 = rr[0], q1 = rr[1];
        union { float4 f4; __half2 h2[4]; } v0, v1;
        v0.f4 = q0; v1.f4 = q1;
        float hv[16];
        const float* a = acc + ld * 33 + hb;
#pragma unroll
        for (int k = 0; k < 4; ++k) {
            float2 xx = __half22float2(v0.h2[k]);
            hv[2 * k] = fmaxf(a[2 * k] + xx.x, 0.f);
            hv[2 * k + 1] = fmaxf(a[2 * k + 1] + xx.y, 0.f);
        }
#pragma unroll
        for (int k = 0; k < 4; ++k) {
            float2 xx = __half22float2(v1.h2[k]);
            hv[8 + 2 * k] = fmaxf(a[8 + 2 * k] + xx.x, 0.f);
            hv[8 + 2 * k + 1] = fmaxf(a[8 + 2 * k + 1] + xx.y, 0.f);
        }
#pragma unroll
        for (int k = 0; k < 16; ++k) {
            pr = fmaf(hv[k], sHead[hb + k], pr);
            po = fmaf(hv[k], sHead[32 + hb + k], po);
            vr = fmaf(hv[k], sHead[64 + hb + k], vr);
            vo = fmaf(hv[k], sHead[96 + hb + k], vo);
        }
    }
    pr += __shfl_xor(pr, 1);
    po += __shfl_xor(po, 1);
    vr += __shfl_xor(vr, 1);
    vo += __shfl_xor(vo, 1);
    if (h == 0 && n < NN) {
        pv[n] = make_float2(pr, vr);
        pbase[n] = po + bp[0];
        vbase[n] = vo + bv[0];
    }
}

// ---------------------------------------------------------------------------
// heads_lds: p/v aggregation (2 floats per edge) via LDS accumulators;
// writes dense p,v arrays.
// ---------------------------------------------------------------------------
__global__ void __launch_bounds__(512) heads_lds_k(
    const float2* __restrict__ pv, const float* __restrict__ pbase,
    const float* __restrict__ vbase, const uint2* __restrict__ buckets,
    const int* __restrict__ btot, float* __restrict__ pfull,
    float* __restrict__ vfull)
{
    __shared__ float pacc[SUB];
    __shared__ float vacc[SUB];
    int t = threadIdx.x, g = blockIdx.x;
    if (t < SUB) { pacc[t] = 0.f; vacc[t] = 0.f; }
    __syncthreads();
    int cnt = btot[g];
    if (cnt < 0) cnt = 0;
    if (cnt > BCAP) cnt = BCAP;
    const uint2* bk = buckets + (size_t)g * BCAP;
    for (int i = t; i < cnt; i += 512) {
        uint2 e = bk[i];
        int s = ent_s(e.x);
        float w = ent_w(e.x);
        int ld = e.y & (SUB - 1);
        float2 x = pv[s];
        atomicAdd(&pacc[ld], x.x * w);
        atomicAdd(&vacc[ld], x.y * w);
    }
    __syncthreads();
    if (t < SUB) {
        int n = g * SUB + t;
        if (n < NN) {
            pfull[n] = pacc[t] + pbase[n];
            vfull[n] = vacc[t] + vbase[n];
        }
    }
}

// ---------------------------------------------------------------------------
// Single-block masked softmax over the listed nodes; dense p/v inputs,
// sparse writes (d_out pre-zeroed). exp(-inf)/Z = 0, mask*v = 0 semantics.
// ---------------------------------------------------------------------------
__global__ void __launch_bounds__(256) masked_softmax_k(
    const int* __restrict__ mlist, const int* __restrict__ mcount,
    const float* __restrict__ pfull, const float* __restrict__ vfull,
    float* __restrict__ out_p, float* __restrict__ out_v)
{
    __shared__ float sPm[MCAP];
    __shared__ int sN[MCAP];
    __shared__ float sMx, sSum;
    __shared__ float sred[4];
    int m = mcount[0];
    if (m > MCAP) m = MCAP;
    if (m < 0) m = 0;
    for (int idx = threadIdx.x; idx < m; idx += 256) {
        int n = mlist[idx];
        if ((unsigned)n >= (unsigned)NN) n = 0;
        sN[idx] = n;
        float p = pfull[n];
        sPm[idx] = (p == 0.f) ? -INFINITY : p;  // jnp.where(p_m==0,-inf,p_m)
    }
    __syncthreads();
    float mx = -INFINITY;
    for (int i = threadIdx.x; i < m; i += 256) mx = fmaxf(mx, sPm[i]);
#pragma unroll
    for (int k = 32; k; k >>= 1) mx = fmaxf(mx, __shfl_xor(mx, k, 64));
    if ((threadIdx.x & 63) == 0) sred[threadIdx.x >> 6] = mx;
    __syncthreads();
    if (threadIdx.x == 0)
        sMx = fmaxf(fmaxf(sred[0], sred[1]), fmaxf(sred[2], sred[3]));
    __syncthreads();
    float sum = 0.f;
    for (int i = threadIdx.x; i < m; i += 256) {
        float x = sPm[i];
        sum += (x == -INFINITY) ? 0.f : expf(x - sMx);
    }
#pragma unroll
    for (int k = 32; k; k >>= 1) sum += __shfl_xor(sum, k, 64);
    if ((threadIdx.x & 63) == 0) sred[threadIdx.x >> 6] = sum;
    __syncthreads();
    if (threadIdx.x == 0) sSum = sred[0] + sred[1] + sred[2] + sred[3];
    __syncthreads();
    for (int idx = threadIdx.x; idx < m; idx += 256) {
        int n = sN[idx];
        float x = sPm[idx];
        out_p[n] = (x == -INFINITY) ? 0.f : expf(x - sMx) / sSum;
        out_v[n] = vfull[n];
    }
}

// ---------------------------------------------------------------------------
extern "C" void kernel_launch(void* const* d_in, const int* in_sizes, int n_in,
                              void* d_out, int out_size, void* d_ws,
                              size_t ws_size, hipStream_t stream)
{
    const float* x        = (const float*)d_in[0];
    const int*   ei       = (const int*)d_in[1];
    const float* ew       = (const float*)d_in[2];
    const int*   cur      = (const int*)d_in[3];
    const float* Win_rel  = (const float*)d_in[4];
    const float* bin_rel  = (const float*)d_in[5];
    const float* Win_root = (const float*)d_in[6];
    const float* Wh_rel   = (const float*)d_in[7];
    const float* bh_rel   = (const float*)d_in[8];
    const float* Wh_root  = (const float*)d_in[9];
    const float* Wp_rel   = (const float*)d_in[10];
    const float* bp       = (const float*)d_in[11];
    const float* Wp_root  = (const float*)d_in[12];
    const float* Wv_rel   = (const float*)d_in[13];
    const float* bv       = (const float*)d_in[14];
    const float* Wv_root  = (const float*)d_in[15];

    const int* srcA = ei;
    const int* dstA = ei + NE;

    // Workspace (~50.3 MB):
    //   buckets | maskb/mcount/mlist/btot | proj1 root1 h1 proj2 root2 | pv pbase vbase
    // Overlays in the proj1 region (disjoint lifetimes):
    //   blkcnt/blkbase (pre-mm1) ; pfull/vfull (post-agg1_lds)
    char* w8 = (char*)d_ws;
    uint2* buckets = (uint2*)w8;                         // NSUB*BCAP*8 = 16.27 MB
    int* maskb  = (int*)(buckets + (size_t)NSUB * BCAP); // NN } zeroed
    int* mcount = maskb + NN;                            // 8  } together
    int* mlist  = mcount + 8;                            // MCAP
    int* btot   = mlist + MCAP;                          // NSUB (pad 400)
    __half* proj1 = (__half*)(btot + 400);
    __half* root1 = proj1 + NW;
    __half* h1    = root1 + NW;
    __half* proj2 = h1 + NW;
    __half* root2 = proj2 + NW;
    float2* pv    = (float2*)(root2 + NW);               // 800 KB
    float* pbase  = (float*)(pv + NN);                   // 400 KB
    float* vbase  = pbase + NN;                          // 400 KB
    // overlays:
    int* blkcnt  = (int*)proj1;                          // NSUB*NCH ints
    int* blkbase = blkcnt + NSUB * NCH;
    float* pfull = (float*)proj1;                        // after agg1_lds
    float* vfull = pfull + NN;

    float* out_p = (float*)d_out;
    float* out_v = out_p + NN;

    const int NB_MM = (NN + 127) / 128;   // 782

    hipMemsetAsync(maskb, 0, ((size_t)NN + 8) * sizeof(int), stream);
    hipMemsetAsync(d_out, 0, 2 * (size_t)NN * sizeof(float), stream);

    // --- bucket build (deterministic, no global reservation atomics) ---
    countC_k<<<NCH, 512, 0, stream>>>(srcA, dstA, cur, maskb, mcount, mlist,
                                      blkcnt);
    scan_blk_k<<<NSUB, 256, 0, stream>>>(blkcnt, blkbase, btot);
    writeC_k<<<NCH, 512, 0, stream>>>(srcA, dstA, ew, blkbase, buckets);

    // --- layer chain with LDS-accumulator aggregation (no CSR) ---
    mm1_k<<<NB_MM, 256, 0, stream>>>(x, Win_rel, Win_root, bin_rel, proj1,
                                     root1);
    agg1_lds_k<<<NSUB, 512, 0, stream>>>(proj1, root1, buckets, btot, h1);
    mm2_k<<<NB_MM, 256, 0, stream>>>(h1, Wh_rel, Wh_root, bh_rel, proj2, root2);
    agg2_lds_k<<<NSUB, 512, 0, stream>>>(proj2, root2, Wp_rel, Wp_root, bp,
                                         Wv_rel, Wv_root, bv, buckets, btot,
                                         pv, pbase, vbase);
    heads_lds_k<<<NSUB, 512, 0, stream>>>(pv, pbase, vbase, buckets, btot,
                                          pfull, vfull);
    // --- masked softmax (sparse outputs) ---
    masked_softmax_k<<<1, 256, 0, stream>>>(mlist, mcount, pfull, vfull, out_p,
                                            out_v);
}

// Round 15
// 262.618 us; speedup vs baseline: 3.3438x; 3.3438x over previous
//
#include <hip/hip_runtime.h>
#include <hip/hip_fp16.h>
#include <cmath>

static constexpr int NN = 100000;   // nodes
static constexpr int NE = 1600000;  // edges
static const size_t NW = (size_t)NN * 32;
static constexpr int SUB = 256;         // nodes per sub-slice
static constexpr int NSUB = 391;        // ceil(NN/SUB)
static constexpr int CH = 8192;         // edges per bucket-build chunk
static constexpr int NCH = (NE + CH - 1) / CH;  // 196
static constexpr int BCAP = 5200;       // per-sub-slice bucket cap (mean 4092)
static constexpr int MCAP = 4096;       // masked-node list capacity

// entry: x = src(17b) | fp16(ew)<<17 ; y = global dst
__device__ __forceinline__ float ent_w(unsigned e)
{
    return __half2float(__ushort_as_half((unsigned short)(e >> 17)));
}
__device__ __forceinline__ int ent_s(unsigned e)
{
    int s = (int)(e & 0x1FFFF);
    return s < NN ? s : NN - 1;   // hardened: OOB -> wrong value, not fault
}

__device__ __forceinline__ float4 pack8(const float* v)
{
    union { __half2 h2[4]; float4 f4; } u;
    u.h2[0] = __floats2half2_rn(v[0], v[1]);
    u.h2[1] = __floats2half2_rn(v[2], v[3]);
    u.h2[2] = __floats2half2_rn(v[4], v[5]);
    u.h2[3] = __floats2half2_rn(v[6], v[7]);
    return u.f4;
}

// ---------------------------------------------------------------------------
// countC: per-(chunk, sub-slice) histogram via LDS + mask collection.
// No global deg atomics (deg/off come from sortB).
// ---------------------------------------------------------------------------
__global__ void __launch_bounds__(512) countC_k(
    const int* __restrict__ src, const int* __restrict__ dst,
    const int* __restrict__ curp, int* __restrict__ maskb,
    int* __restrict__ mcount, int* __restrict__ mlist,
    int* __restrict__ blkcnt)
{
    __shared__ int lhist[NSUB];
    int t = threadIdx.x;
    for (int i = t; i < NSUB; i += 512) lhist[i] = 0;
    __syncthreads();
    int c0 = blockIdx.x * CH;
    int cur = curp[0];
#pragma unroll
    for (int it = 0; it < CH / 512; ++it) {
        int e = c0 + it * 512 + t;
        if (e < NE) {
            int d = dst[e];
            if ((unsigned)d < (unsigned)NN) {
                atomicAdd(&lhist[d >> 8], 1);
                if (src[e] == cur) {
                    if (atomicExch(maskb + d, 1) == 0) {
                        int idx = atomicAdd(mcount, 1);
                        if (idx < MCAP) mlist[idx] = d;
                    }
                }
            }
        }
    }
    __syncthreads();
    for (int b = t; b < NSUB; b += 512)
        blkcnt[b * NCH + blockIdx.x] = lhist[b];
}

// scan chunks within each sub-slice: blkbase (excl), btot. NCH=196 < 256.
__global__ void __launch_bounds__(256) scan_blk_k(
    const int* __restrict__ blkcnt, int* __restrict__ blkbase,
    int* __restrict__ btot)
{
    __shared__ int tmp[256];
    int b = blockIdx.x, t = threadIdx.x;
    int v = (t < NCH) ? blkcnt[b * NCH + t] : 0;
    tmp[t] = v;
    __syncthreads();
    for (int s = 1; s < 256; s <<= 1) {
        int x = tmp[t];
        int a = (t >= s) ? tmp[t - s] : 0;
        __syncthreads();
        tmp[t] = x + a;
        __syncthreads();
    }
    if (t < NCH) blkbase[b * NCH + t] = tmp[t] - v;
    if (t == 255) btot[b] = tmp[255];
}

// exclusive scan of btot[NSUB] -> gbase (global csr base per sub-slice).
__global__ void __launch_bounds__(512) scan_btot_k(
    const int* __restrict__ btot, int* __restrict__ gbase)
{
    __shared__ int tmp[512];
    int t = threadIdx.x;
    int v = (t < NSUB) ? btot[t] : 0;
    tmp[t] = v;
    __syncthreads();
    for (int s = 1; s < 512; s <<= 1) {
        int x = tmp[t];
        int a = (t >= s) ? tmp[t - s] : 0;
        __syncthreads();
        tmp[t] = x + a;
        __syncthreads();
    }
    if (t < NSUB) gbase[t] = tmp[t] - v;
}

// ---------------------------------------------------------------------------
// writeC: stage chunk in registers, LDS-sort by sub-slice, dump grouped
// (consecutive threads -> consecutive bucket addresses). Deterministic bases.
// ---------------------------------------------------------------------------
__global__ void __launch_bounds__(512) writeC_k(
    const int* __restrict__ src, const int* __restrict__ dst,
    const float* __restrict__ ew, const int* __restrict__ blkbase,
    uint2* __restrict__ buckets)
{
    __shared__ uint2 sBuf[CH];          // 64 KB
    __shared__ int lhist[NSUB];
    __shared__ int lpos[NSUB];
    __shared__ int lstart[NSUB];
    __shared__ int lbase[NSUB];
    __shared__ int tscan[512];
    int t = threadIdx.x;
    for (int i = t; i < NSUB; i += 512) { lhist[i] = 0; lpos[i] = 0; }
    __syncthreads();
    int c0 = blockIdx.x * CH;
    uint2 rent[CH / 512];
    int rb[CH / 512];
#pragma unroll
    for (int it = 0; it < CH / 512; ++it) {
        int e = c0 + it * 512 + t;
        rb[it] = -1;
        if (e < NE) {
            int d = dst[e];
            if ((unsigned)d < (unsigned)NN) {
                rb[it] = d >> 8;
                unsigned bits = __half_as_ushort(__float2half(ew[e]));
                rent[it].x = ((unsigned)src[e] & 0x1FFFF) | (bits << 17);
                rent[it].y = (unsigned)d;
                atomicAdd(&lhist[rb[it]], 1);
            }
        }
    }
    __syncthreads();
    int v = (t < NSUB) ? lhist[t] : 0;
    tscan[t] = v;
    __syncthreads();
    for (int s = 1; s < 512; s <<= 1) {
        int x = tscan[t];
        int a = (t >= s) ? tscan[t - s] : 0;
        __syncthreads();
        tscan[t] = x + a;
        __syncthreads();
    }
    if (t < NSUB) {
        lstart[t] = tscan[t] - v;
        lbase[t] = blkbase[t * NCH + blockIdx.x];
    }
    __syncthreads();
#pragma unroll
    for (int it = 0; it < CH / 512; ++it) {
        if (rb[it] >= 0) {
            int p = atomicAdd(&lpos[rb[it]], 1);
            sBuf[lstart[rb[it]] + p] = rent[it];
        }
    }
    __syncthreads();
    int total = lstart[NSUB - 1] + lhist[NSUB - 1];
    for (int j = t; j < total; j += 512) {
        uint2 e = sBuf[j];
        int b = (int)(e.y >> 8);
        if (b >= NSUB) b = NSUB - 1;
        unsigned pos = (unsigned)(lbase[b] + (j - lstart[b]));
        if (pos < (unsigned)BCAP) buckets[(size_t)b * BCAP + pos] = e;
    }
}

// ---------------------------------------------------------------------------
// sortB: per-sub-slice LDS counting sort -> contiguous csr segment at
// gbase[g]; also writes deg/off densely. Inner loop is LDS-only (no random
// global gathers — the R14 failure mode), output writes are line-dense.
// ---------------------------------------------------------------------------
__global__ void __launch_bounds__(512) sortB_k(
    const uint2* __restrict__ buckets, const int* __restrict__ btot,
    const int* __restrict__ gbase, unsigned* __restrict__ csr4,
    int* __restrict__ deg, int* __restrict__ off)
{
    __shared__ uint2 sBuf[BCAP];    // 41.6 KB
    __shared__ int lhist[SUB];
    __shared__ int lstart[SUB];
    __shared__ int lcur[SUB];
    __shared__ int tscan[256];
    int g = blockIdx.x, t = threadIdx.x;
    if (t < SUB) { lhist[t] = 0; lcur[t] = 0; }
    __syncthreads();
    int cnt = btot[g];
    if (cnt < 0) cnt = 0;
    if (cnt > BCAP) cnt = BCAP;
    const uint2* bk = buckets + (size_t)g * BCAP;
    for (int i = t; i < cnt; i += 512) {
        uint2 e = bk[i];
        sBuf[i] = e;
        atomicAdd(&lhist[e.y & (SUB - 1)], 1);
    }
    __syncthreads();
    if (t < 256) tscan[t] = lhist[t];
    __syncthreads();
    for (int s = 1; s < 256; s <<= 1) {
        int x = 0, a = 0;
        if (t < 256) { x = tscan[t]; a = (t >= s) ? tscan[t - s] : 0; }
        __syncthreads();
        if (t < 256) tscan[t] = x + a;
        __syncthreads();
    }
    if (t < 256) lstart[t] = tscan[t] - lhist[t];
    __syncthreads();
    int base = gbase[g];
    for (int i = t; i < cnt; i += 512) {
        uint2 e = sBuf[i];
        int ld = (int)(e.y & (SUB - 1));
        int p = atomicAdd(&lcur[ld], 1);
        unsigned pos = (unsigned)(base + lstart[ld] + p);
        if (pos < (unsigned)NE) csr4[pos] = e.x;
    }
    if (t < SUB) {
        int n = g * SUB + t;
        if (n < NN) {
            deg[n] = lhist[t];
            off[n] = base + lstart[t];
        }
    }
}

// ---------------------------------------------------------------------------
// mm1: proj1 = fp16(x@Win_rel), root1 = fp16(x@Win_root + bin).
// ---------------------------------------------------------------------------
__global__ void __launch_bounds__(256) mm1_k(
    const float* __restrict__ x, const float* __restrict__ Wrel,
    const float* __restrict__ Wroot, const float* __restrict__ bin,
    __half* __restrict__ proj1, __half* __restrict__ root1)
{
    __shared__ float sX[128 * 65];
    __shared__ float sW[64 * 68];
    int t = threadIdx.x;
    for (int i = t; i < 64 * 32; i += 256) {
        int k = i >> 5, j = i & 31;
        sW[k * 68 + j] = Wrel[i];
        sW[k * 68 + 32 + j] = Wroot[i];
    }
    int base = blockIdx.x * 128;
    for (int i = t; i < 2048; i += 256) {
        int node = i >> 4;
        int k = (i & 15) * 4;
        int n = base + node;
        if (n >= NN) n = NN - 1;
        float4 v = *(const float4*)(x + (size_t)n * 64 + k);
        float* p = sX + node * 65 + k;
        p[0] = v.x; p[1] = v.y; p[2] = v.z; p[3] = v.w;
    }
    __syncthreads();
    int cg = t & 7;
    int ng = t >> 3;
    int c0 = 8 * cg;
    float acc[4][8] = {};
    for (int k = 0; k < 64; ++k) {
        float xv0 = sX[(4 * ng + 0) * 65 + k];
        float xv1 = sX[(4 * ng + 1) * 65 + k];
        float xv2 = sX[(4 * ng + 2) * 65 + k];
        float xv3 = sX[(4 * ng + 3) * 65 + k];
        float4 w0 = *(const float4*)(sW + k * 68 + c0);
        float4 w1 = *(const float4*)(sW + k * 68 + c0 + 4);
        const float* wp = (const float*)&w0;
#pragma unroll
        for (int j = 0; j < 4; ++j) {
            float w = wp[j];
            acc[0][j] = fmaf(xv0, w, acc[0][j]);
            acc[1][j] = fmaf(xv1, w, acc[1][j]);
            acc[2][j] = fmaf(xv2, w, acc[2][j]);
            acc[3][j] = fmaf(xv3, w, acc[3][j]);
        }
        const float* wq = (const float*)&w1;
#pragma unroll
        for (int j = 0; j < 4; ++j) {
            float w = wq[j];
            acc[0][4 + j] = fmaf(xv0, w, acc[0][4 + j]);
            acc[1][4 + j] = fmaf(xv1, w, acc[1][4 + j]);
            acc[2][4 + j] = fmaf(xv2, w, acc[2][4 + j]);
            acc[3][4 + j] = fmaf(xv3, w, acc[3][4 + j]);
        }
    }
#pragma unroll
    for (int r = 0; r < 4; ++r) {
        int n = base + 4 * ng + r;
        if (n >= NN) break;
        if (cg < 4) {
            *(float4*)(proj1 + (size_t)n * 32 + c0) = pack8(acc[r]);
        } else {
            int c = c0 - 32;
            float v[8];
#pragma unroll
            for (int j = 0; j < 8; ++j) v[j] = acc[r][j] + bin[c + j];
            *(float4*)(root1 + (size_t)n * 32 + c) = pack8(v);
        }
    }
}

// ---------------------------------------------------------------------------
// mm2: proj2 = fp16(h1@Wh_rel), root2 = fp16(h1@Wh_root + bh). K=32.
// ---------------------------------------------------------------------------
__global__ void __launch_bounds__(256) mm2_k(
    const __half* __restrict__ h1, const float* __restrict__ Wrel,
    const float* __restrict__ Wroot, const float* __restrict__ bh,
    __half* __restrict__ proj2, __half* __restrict__ root2)
{
    __shared__ float sX[128 * 33];
    __shared__ float sW[32 * 68];
    int t = threadIdx.x;
    for (int i = t; i < 32 * 32; i += 256) {
        int k = i >> 5, j = i & 31;
        sW[k * 68 + j] = Wrel[i];
        sW[k * 68 + 32 + j] = Wroot[i];
    }
    int base = blockIdx.x * 128;
    for (int i = t; i < 512; i += 256) {
        int node = i >> 2;
        int hs = (i & 3) * 8;
        int n = base + node;
        if (n >= NN) n = NN - 1;
        float4 v = *(const float4*)(h1 + (size_t)n * 32 + hs);
        const __half2* hp = (const __half2*)&v;
        float* p = sX + node * 33 + hs;
#pragma unroll
        for (int u = 0; u < 4; ++u) {
            float2 f2 = __half22float2(hp[u]);
            p[2 * u] = f2.x;
            p[2 * u + 1] = f2.y;
        }
    }
    __syncthreads();
    int cg = t & 7;
    int ng = t >> 3;
    int c0 = 8 * cg;
    float acc[4][8] = {};
    for (int k = 0; k < 32; ++k) {
        float xv0 = sX[(4 * ng + 0) * 33 + k];
        float xv1 = sX[(4 * ng + 1) * 33 + k];
        float xv2 = sX[(4 * ng + 2) * 33 + k];
        float xv3 = sX[(4 * ng + 3) * 33 + k];
        float4 w0 = *(const float4*)(sW + k * 68 + c0);
        float4 w1 = *(const float4*)(sW + k * 68 + c0 + 4);
        const float* wp = (const float*)&w0;
#pragma unroll
        for (int j = 0; j < 4; ++j) {
            float w = wp[j];
            acc[0][j] = fmaf(xv0, w, acc[0][j]);
            acc[1][j] = fmaf(xv1, w, acc[1][j]);
            acc[2][j] = fmaf(xv2, w, acc[2][j]);
            acc[3][j] = fmaf(xv3, w, acc[3][j]);
        }
        const float* wq = (const float*)&w1;
#pragma unroll
        for (int j = 0; j < 4; ++j) {
            float w = wq[j];
            acc[0][4 + j] = fmaf(xv0, w, acc[0][4 + j]);
            acc[1][4 + j] = fmaf(xv1, w, acc[1][4 + j]);
            acc[2][4 + j] = fmaf(xv2, w, acc[2][4 + j]);
            acc[3][4 + j] = fmaf(xv3, w, acc[3][4 + j]);
        }
    }
#pragma unroll
    for (int r = 0; r < 4; ++r) {
        int n = base + 4 * ng + r;
        if (n >= NN) break;
        if (cg < 4) {
            *(float4*)(proj2 + (size_t)n * 32 + c0) = pack8(acc[r]);
        } else {
            int c = c0 - 32;
            float v[8];
#pragma unroll
            for (int j = 0; j < 8; ++j) v[j] = acc[r][j] + bh[c + j];
            *(float4*)(root2 + (size_t)n * 32 + c) = pack8(v);
        }
    }
}

// ---------------------------------------------------------------------------
// agg1 v4: 4 lanes per node (q = feature octet), 16 nodes/wave.
// ---------------------------------------------------------------------------
__global__ void __launch_bounds__(256) agg1_v4(
    const __half* __restrict__ proj1, const __half* __restrict__ root1,
    const unsigned* __restrict__ csr4, const int* __restrict__ off,
    const int* __restrict__ deg, __half* __restrict__ h1)
{
    int t = threadIdx.x;
    int q = t & 3;
    int f0 = q * 8;
    int n = blockIdx.x * 64 + (t >> 2);
    if (n >= NN) return;
    int st = off[n];
    int dg = deg[n];
    if (st < 0) st = 0;
    if (st > NE) st = NE;
    if (dg < 0) dg = 0;
    if (dg > NE - st) dg = NE - st;
    float acc[8] = {0.f, 0.f, 0.f, 0.f, 0.f, 0.f, 0.f, 0.f};
    int i = 0;
    for (; i + 1 < dg; i += 2) {
        unsigned e0 = csr4[st + i];
        unsigned e1 = csr4[st + i + 1];
        float w0 = ent_w(e0), w1 = ent_w(e1);
        float4 r0 = *(const float4*)(proj1 + (size_t)ent_s(e0) * 32 + f0);
        float4 r1 = *(const float4*)(proj1 + (size_t)ent_s(e1) * 32 + f0);
        const __half2* h0 = (const __half2*)&r0;
        const __half2* h1p = (const __half2*)&r1;
#pragma unroll
        for (int u = 0; u < 4; ++u) {
            float2 a = __half22float2(h0[u]);
            float2 b = __half22float2(h1p[u]);
            acc[2 * u] = fmaf(w0, a.x, acc[2 * u]);
            acc[2 * u + 1] = fmaf(w0, a.y, acc[2 * u + 1]);
            acc[2 * u] = fmaf(w1, b.x, acc[2 * u]);
            acc[2 * u + 1] = fmaf(w1, b.y, acc[2 * u + 1]);
        }
    }
    if (i < dg) {
        unsigned e0 = csr4[st + i];
        float w0 = ent_w(e0);
        float4 r0 = *(const float4*)(proj1 + (size_t)ent_s(e0) * 32 + f0);
        const __half2* h0 = (const __half2*)&r0;
#pragma unroll
        for (int u = 0; u < 4; ++u) {
            float2 a = __half22float2(h0[u]);
            acc[2 * u] = fmaf(w0, a.x, acc[2 * u]);
            acc[2 * u + 1] = fmaf(w0, a.y, acc[2 * u + 1]);
        }
    }
    float4 rr = *(const float4*)(root1 + (size_t)n * 32 + f0);
    const __half2* rp = (const __half2*)&rr;
    float h[8];
#pragma unroll
    for (int u = 0; u < 4; ++u) {
        float2 f2 = __half22float2(rp[u]);
        h[2 * u] = fmaxf(acc[2 * u] + f2.x, 0.f);
        h[2 * u + 1] = fmaxf(acc[2 * u + 1] + f2.y, 0.f);
    }
    *(float4*)(h1 + (size_t)n * 32 + f0) = pack8(h);
}

// ---------------------------------------------------------------------------
// agg2 v4: same gather structure; epilogue computes the 4 OUT=1 head dots.
// ---------------------------------------------------------------------------
__global__ void __launch_bounds__(256) agg2_v4(
    const __half* __restrict__ proj2, const __half* __restrict__ root2,
    const float* __restrict__ Wp_rel, const float* __restrict__ Wp_root,
    const float* __restrict__ bp, const float* __restrict__ Wv_rel,
    const float* __restrict__ Wv_root, const float* __restrict__ bv,
    const unsigned* __restrict__ csr4, const int* __restrict__ off,
    const int* __restrict__ deg, float2* __restrict__ pv,
    float* __restrict__ pbase, float* __restrict__ vbase)
{
    __shared__ float sHead[4 * 32];
    if (threadIdx.x < 32) {
        sHead[threadIdx.x] = Wp_rel[threadIdx.x];
        sHead[32 + threadIdx.x] = Wp_root[threadIdx.x];
        sHead[64 + threadIdx.x] = Wv_rel[threadIdx.x];
        sHead[96 + threadIdx.x] = Wv_root[threadIdx.x];
    }
    __syncthreads();
    int t = threadIdx.x;
    int q = t & 3;
    int f0 = q * 8;
    int n = blockIdx.x * 64 + (t >> 2);
    if (n >= NN) return;
    int st = off[n];
    int dg = deg[n];
    if (st < 0) st = 0;
    if (st > NE) st = NE;
    if (dg < 0) dg = 0;
    if (dg > NE - st) dg = NE - st;
    float acc[8] = {0.f, 0.f, 0.f, 0.f, 0.f, 0.f, 0.f, 0.f};
    int i = 0;
    for (; i + 1 < dg; i += 2) {
        unsigned e0 = csr4[st + i];
        unsigned e1 = csr4[st + i + 1];
        float w0 = ent_w(e0), w1 = ent_w(e1);
        float4 r0 = *(const float4*)(proj2 + (size_t)ent_s(e0) * 32 + f0);
        float4 r1 = *(const float4*)(proj2 + (size_t)ent_s(e1) * 32 + f0);
        const __half2* h0 = (const __half2*)&r0;
        const __half2* h1p = (const __half2*)&r1;
#pragma unroll
        for (int u = 0; u < 4; ++u) {
            float2 a = __half22float2(h0[u]);
            float2 b = __half22float2(h1p[u]);
            acc[2 * u] = fmaf(w0, a.x, acc[2 * u]);
            acc[2 * u + 1] = fmaf(w0, a.y, acc[2 * u + 1]);
            acc[2 * u] = fmaf(w1, b.x, acc[2 * u]);
            acc[2 * u + 1] = fmaf(w1, b.y, acc[2 * u + 1]);
        }
    }
    if (i < dg) {
        unsigned e0 = csr4[st + i];
        float w0 = ent_w(e0);
        float4 r0 = *(const float4*)(proj2 + (size_t)ent_s(e0) * 32 + f0);
        const __half2* h0 = (const __half2*)&r0;
#pragma unroll
        for (int u = 0; u < 4; ++u) {
            float2 a = __half22float2(h0[u]);
            acc[2 * u] = fmaf(w0, a.x, acc[2 * u]);
            acc[2 * u + 1] = fmaf(w0, a.y, acc[2 * u + 1]);
        }
    }
    float4 rr = *(const float4*)(root2 + (size_t)n * 32 + f0);
    const __half2* rp = (const __half2*)&rr;
    float h[8];
#pragma unroll
    for (int u = 0; u < 4; ++u) {
        float2 f2 = __half22float2(rp[u]);
        h[2 * u] = fmaxf(acc[2 * u] + f2.x, 0.f);
        h[2 * u + 1] = fmaxf(acc[2 * u + 1] + f2.y, 0.f);
    }
    float prv = 0.f, pov = 0.f, vrv = 0.f, vov = 0.f;
#pragma unroll
    for (int j = 0; j < 8; ++j) {
        prv = fmaf(h[j], sHead[f0 + j], prv);
        pov = fmaf(h[j], sHead[32 + f0 + j], pov);
        vrv = fmaf(h[j], sHead[64 + f0 + j], vrv);
        vov = fmaf(h[j], sHead[96 + f0 + j], vov);
    }
#pragma unroll
    for (int m = 1; m <= 2; m <<= 1) {
        prv += __shfl_xor(prv, m, 64);
        pov += __shfl_xor(pov, m, 64);
        vrv += __shfl_xor(vrv, m, 64);
        vov += __shfl_xor(vov, m, 64);
    }
    if (q == 0) {
        pv[n] = make_float2(prv, vrv);
        pbase[n] = pov + bp[0];
        vbase[n] = vov + bv[0];
    }
}

// ---------------------------------------------------------------------------
// Single-block masked softmax over the listed nodes; sparse writes.
// ---------------------------------------------------------------------------
__global__ void __launch_bounds__(256) masked_softmax_k(
    const int* __restrict__ mlist, const int* __restrict__ mcount,
    const unsigned* __restrict__ csr4, const int* __restrict__ off,
    const int* __restrict__ deg, const float2* __restrict__ pv,
    const float* __restrict__ pbase, const float* __restrict__ vbase,
    float* __restrict__ out_p, float* __restrict__ out_v)
{
    __shared__ float sPm[MCAP];
    __shared__ float sV[MCAP];
    __shared__ int sN[MCAP];
    __shared__ float sMx, sSum;
    __shared__ float sred[4];
    int m = mcount[0];
    if (m > MCAP) m = MCAP;
    if (m < 0) m = 0;
    for (int idx = threadIdx.x; idx < m; idx += 256) {
        int n = mlist[idx];
        if ((unsigned)n >= (unsigned)NN) n = 0;
        sN[idx] = n;
        int st = off[n];
        int dg = deg[n];
        if (st < 0) st = 0;
        if (st > NE) st = NE;
        if (dg < 0) dg = 0;
        if (dg > NE - st) dg = NE - st;
        float pa = 0.f, va = 0.f;
        for (int i = 0; i < dg; ++i) {
            unsigned ent = csr4[st + i];
            int s = ent_s(ent);
            float w = ent_w(ent);
            float2 tv = pv[s];
            pa = fmaf(tv.x, w, pa);
            va = fmaf(tv.y, w, va);
        }
        float p = pa + pbase[n];
        sPm[idx] = (p == 0.f) ? -INFINITY : p;
        sV[idx] = va + vbase[n];
    }
    __syncthreads();
    float mx = -INFINITY;
    for (int i = threadIdx.x; i < m; i += 256) mx = fmaxf(mx, sPm[i]);
#pragma unroll
    for (int k = 32; k; k >>= 1) mx = fmaxf(mx, __shfl_xor(mx, k, 64));
    if ((threadIdx.x & 63) == 0) sred[threadIdx.x >> 6] = mx;
    __syncthreads();
    if (threadIdx.x == 0)
        sMx = fmaxf(fmaxf(sred[0], sred[1]), fmaxf(sred[2], sred[3]));
    __syncthreads();
    float sum = 0.f;
    for (int i = threadIdx.x; i < m; i += 256) {
        float x = sPm[i];
        sum += (x == -INFINITY) ? 0.f : expf(x - sMx);
    }
#pragma unroll
    for (int k = 32; k; k >>= 1) sum += __shfl_xor(sum, k, 64);
    if ((threadIdx.x & 63) == 0) sred[threadIdx.x >> 6] = sum;
    __syncthreads();
    if (threadIdx.x == 0) sSum = sred[0] + sred[1] + sred[2] + sred[3];
    __syncthreads();
    for (int idx = threadIdx.x; idx < m; idx += 256) {
        int n = sN[idx];
        float x = sPm[idx];
        out_p[n] = (x == -INFINITY) ? 0.f : expf(x - sMx) / sSum;
        out_v[n] = sV[idx];
    }
}

// ---------------------------------------------------------------------------
extern "C" void kernel_launch(void* const* d_in, const int* in_sizes, int n_in,
                              void* d_out, int out_size, void* d_ws,
                              size_t ws_size, hipStream_t stream)
{
    const float* x        = (const float*)d_in[0];
    const int*   ei       = (const int*)d_in[1];
    const float* ew       = (const float*)d_in[2];
    const int*   cur      = (const int*)d_in[3];
    const float* Win_rel  = (const float*)d_in[4];
    const float* bin_rel  = (const float*)d_in[5];
    const float* Win_root = (const float*)d_in[6];
    const float* Wh_rel   = (const float*)d_in[7];
    const float* bh_rel   = (const float*)d_in[8];
    const float* Wh_root  = (const float*)d_in[9];
    const float* Wp_rel   = (const float*)d_in[10];
    const float* bp       = (const float*)d_in[11];
    const float* Wp_root  = (const float*)d_in[12];
    const float* Wv_rel   = (const float*)d_in[13];
    const float* bv       = (const float*)d_in[14];
    const float* Wv_root  = (const float*)d_in[15];

    const int* srcA = ei;
    const int* dstA = ei + NE;

    // Workspace (~41.5 MB):
    //   csr4 | deg | off | maskb | mcount/mlist/btot/gbase | U(32MB) | pv/pbase/vbase
    // U overlays (all dead before mm1 writes proj1):
    //   buckets (16.27MB) + blkcnt + blkbase
    char* w8 = (char*)d_ws;
    unsigned* csr4 = (unsigned*)w8;          // 6.4 MB
    int* deg    = (int*)(csr4 + NE);         // NN
    int* off    = deg + NN;                  // NN
    int* maskb  = off + NN;                  // NN } zeroed
    int* mcount = maskb + NN;                // 8  } together
    int* mlist  = mcount + 8;                // MCAP
    int* btot   = mlist + MCAP;              // NSUB (pad 400)
    int* gbase  = btot + 400;                // NSUB (pad 400)
    __half* proj1 = (__half*)(gbase + 400);  // U start
    __half* root1 = proj1 + NW;
    __half* h1    = root1 + NW;
    __half* proj2 = h1 + NW;
    __half* root2 = proj2 + NW;
    float2* pv    = (float2*)(root2 + NW);   // 800 KB
    float* pbase  = (float*)(pv + NN);       // 400 KB
    float* vbase  = pbase + NN;              // 400 KB
    // overlays in U:
    uint2* buckets = (uint2*)proj1;                       // 16.27 MB
    int* blkcnt  = (int*)(buckets + (size_t)NSUB * BCAP); // NSUB*NCH
    int* blkbase = blkcnt + NSUB * NCH;

    float* out_p = (float*)d_out;
    float* out_v = out_p + NN;

    const int NB_MM  = (NN + 127) / 128;   // 782
    const int NB_AGG = (NN + 63) / 64;     // 1563

    hipMemsetAsync(maskb, 0, ((size_t)NN + 8) * sizeof(int), stream);
    hipMemsetAsync(d_out, 0, 2 * (size_t)NN * sizeof(float), stream);

    // --- CSR build: deterministic bucket + per-sub-slice LDS counting sort
    countC_k<<<NCH, 512, 0, stream>>>(srcA, dstA, cur, maskb, mcount, mlist,
                                      blkcnt);
    scan_blk_k<<<NSUB, 256, 0, stream>>>(blkcnt, blkbase, btot);
    scan_btot_k<<<1, 512, 0, stream>>>(btot, gbase);
    writeC_k<<<NCH, 512, 0, stream>>>(srcA, dstA, ew, blkbase, buckets);
    sortB_k<<<NSUB, 512, 0, stream>>>(buckets, btot, gbase, csr4, deg, off);

    // --- layer chain ---
    mm1_k<<<NB_MM, 256, 0, stream>>>(x, Win_rel, Win_root, bin_rel, proj1,
                                     root1);
    agg1_v4<<<NB_AGG, 256, 0, stream>>>(proj1, root1, csr4, off, deg, h1);
    mm2_k<<<NB_MM, 256, 0, stream>>>(h1, Wh_rel, Wh_root, bh_rel, proj2, root2);
    agg2_v4<<<NB_AGG, 256, 0, stream>>>(proj2, root2, Wp_rel, Wp_root, bp,
                                        Wv_rel, Wv_root, bv, csr4, off, deg,
                                        pv, pbase, vbase);
    // --- masked softmax (sparse outputs) ---
    masked_softmax_k<<<1, 256, 0, stream>>>(mlist, mcount, csr4, off, deg, pv,
                                            pbase, vbase, out_p, out_v);
}